// Round 5
// baseline (396.430 us; speedup 1.0000x reference)
//
#include <hip/hip_runtime.h>
#include <hip/hip_fp16.h>

#define TEMP 10.0f
#define TPB 256
#define SHIFT 7
#define GSZ 128           // nodes per bucket = 1<<SHIFT

typedef float v2f __attribute__((ext_vector_type(2)));

__device__ __forceinline__ void pk_fadd(float* p, float a, float b) {
#if __has_builtin(__builtin_amdgcn_global_atomic_fadd_v2f32)
    v2f v; v.x = a; v.y = b;
    __builtin_amdgcn_global_atomic_fadd_v2f32(
        (__attribute__((address_space(1))) v2f*)p, v);
#else
    atomicAdd(p, a); atomicAdd(p + 1, b);
#endif
}

__device__ __forceinline__ void hamilton(float4 a, float4 b,
                                         float& ow, float& ox, float& oy, float& oz) {
    ow = a.x*b.x - a.y*b.y - a.z*b.z - a.w*b.w;
    ox = a.x*b.y + a.y*b.x + a.z*b.w - a.w*b.z;
    oy = a.x*b.z - a.y*b.w + a.z*b.x + a.w*b.y;
    oz = a.x*b.w + a.y*b.z - a.z*b.y + a.w*b.x;
}

__device__ __forceinline__ unsigned f2h(float x) {
    return (unsigned)__half_as_ushort(__float2half_rn(x));
}
__device__ __forceinline__ float h2f(unsigned u) {
    return __half2float(__ushort_as_half((unsigned short)(u & 0xFFFFu)));
}

// ---------- pass H: per-block LDS histogram of dst buckets ----------
__global__ void __launch_bounds__(TPB)
hist_kernel(const int* __restrict__ dst, unsigned* __restrict__ blkhist,
            int E, int B, int span) {
    extern __shared__ unsigned h[];
    for (int i = threadIdx.x; i < B; i += blockDim.x) h[i] = 0;
    __syncthreads();
    int start = blockIdx.x * span;
    int end = start + span; if (end > E) end = E;
    for (int e = start + threadIdx.x; e < end; e += blockDim.x)
        atomicAdd(&h[((unsigned)dst[e]) >> SHIFT], 1u);
    __syncthreads();
    for (int i = threadIdx.x; i < B; i += blockDim.x)
        blkhist[(size_t)i * gridDim.x + blockIdx.x] = h[i];  // bucket-major
}

// ---------- pass P1: exclusive scan across blocks, per bucket ----------
// blockDim.x == NBLK (<=1024)
__global__ void __launch_bounds__(1024)
scan_blocks_kernel(unsigned* __restrict__ blkhist, unsigned* __restrict__ totals) {
    __shared__ unsigned s[1024];
    int b = blockIdx.x, t = threadIdx.x, n = blockDim.x;
    unsigned v = blkhist[(size_t)b * n + t];
    s[t] = v; __syncthreads();
    for (int off = 1; off < n; off <<= 1) {
        unsigned add = (t >= off) ? s[t - off] : 0u;
        __syncthreads();
        s[t] += add;
        __syncthreads();
    }
    blkhist[(size_t)b * n + t] = s[t] - v;   // exclusive (local base)
    if (t == n - 1) totals[b] = s[t];
}

// ---------- pass P2: exclusive scan of bucket totals ----------
__global__ void __launch_bounds__(1024)
scan_totals_kernel(const unsigned* __restrict__ totals,
                   unsigned* __restrict__ offsets, int B) {
    __shared__ unsigned s[1024];
    int t = threadIdx.x;
    unsigned v = (t < B) ? totals[t] : 0u;
    s[t] = v; __syncthreads();
    for (int off = 1; off < 1024; off <<= 1) {
        unsigned add = (t >= off) ? s[t - off] : 0u;
        __syncthreads();
        s[t] += add;
        __syncthreads();
    }
    if (t < B) offsets[t] = s[t] - v;
    if (t == B - 1) offsets[B] = s[t];
}

// ---------- pass S: compute payload, place at exact slot (no global atomics) ----------
__global__ void __launch_bounds__(TPB)
scatter_pay_kernel(const float* __restrict__ nl, const float4* __restrict__ nq,
                   const float4* __restrict__ erq, const float* __restrict__ ew,
                   const int* __restrict__ src, const int* __restrict__ dst,
                   const unsigned* __restrict__ blkhist,
                   const unsigned* __restrict__ offsets,
                   uint4* __restrict__ buckets,
                   int E, int B, int span) {
    extern __shared__ unsigned cur[];
    int blk = blockIdx.x, nb = gridDim.x;
    for (int b = threadIdx.x; b < B; b += blockDim.x)
        cur[b] = offsets[b] + blkhist[(size_t)b * nb + blk];
    __syncthreads();
    int start = blk * span;
    int end = start + span; if (end > E) end = E;
    for (int e = start + threadIdx.x; e < end; e += blockDim.x) {
        int s_ = src[e];
        unsigned d = (unsigned)dst[e];
        float l = nl[s_];
        float p = __expf(TEMP * ew[e] * l);
        float ow, ox, oy, oz;
        hamilton(erq[e], nq[s_], ow, ox, oy, oz);
        unsigned slot = atomicAdd(&cur[d >> SHIFT], 1u);  // LDS cursor
        uint4 pk;
        pk.x = (d & (GSZ - 1)) | (f2h(p) << 16);
        pk.y = f2h(p * l)  | (f2h(p * ow) << 16);
        pk.z = f2h(p * ox) | (f2h(p * oy) << 16);
        pk.w = f2h(p * oz);
        buckets[slot] = pk;
    }
}

// ---------- pass G: per-bucket LDS accumulate + finalize ----------
__global__ void __launch_bounds__(TPB)
gather_pay_kernel(const float* __restrict__ nl, const float4* __restrict__ nq,
                  const unsigned* __restrict__ offsets,
                  const uint4* __restrict__ buckets,
                  float4* __restrict__ out_q, float* __restrict__ out_l, int N) {
    __shared__ float acc[2][GSZ * 7];              // 2 copies: even/odd waves
    int b = blockIdx.x;
    for (int i = threadIdx.x; i < GSZ * 7; i += blockDim.x) {
        acc[0][i] = 0.f; acc[1][i] = 0.f;
    }
    __syncthreads();
    int copy = (threadIdx.x >> 6) & 1;
    unsigned s0 = offsets[b], s1 = offsets[b + 1];
    for (unsigned i = s0 + threadIdx.x; i < s1; i += blockDim.x) {
        uint4 pk = buckets[i];
        unsigned dl = pk.x & 0xFFFFu;
        float p  = h2f(pk.x >> 16);
        float pl = h2f(pk.y);
        float q0 = h2f(pk.y >> 16);
        float q1 = h2f(pk.z);
        float q2 = h2f(pk.z >> 16);
        float q3 = h2f(pk.w);
        float* a = &acc[copy][dl * 7];
        atomicAdd(a + 0, p);  atomicAdd(a + 1, pl);
        atomicAdd(a + 2, q0); atomicAdd(a + 3, q1);
        atomicAdd(a + 4, q2); atomicAdd(a + 5, q3);
    }
    __syncthreads();
    int n0 = b * GSZ;
    for (int j = threadIdx.x; j < GSZ; j += blockDim.x) {
        int n = n0 + j;
        if (n >= N) break;
        float l = nl[n];
        float ps = __expf(TEMP * l);
        const float* a0 = &acc[0][j * 7];
        const float* a1 = &acc[1][j * 7];
        float Z  = a0[0] + a1[0] + ps;
        float sl = a0[1] + a1[1] + ps * l;
        float4 q = nq[n];
        float qw = a0[2] + a1[2] + ps * q.x;
        float qx = a0[3] + a1[3] + ps * q.y;
        float qy = a0[4] + a1[4] + ps * q.z;
        float qz = a0[5] + a1[5] + ps * q.w;
        float inv = 1.0f / Z;
        qw *= inv; qx *= inv; qy *= inv; qz *= inv;
        float norm = fmaxf(sqrtf(qw*qw + qx*qx + qy*qy + qz*qz), 1e-12f);
        float rn = 1.0f / norm;
        out_q[n] = make_float4(qw * rn, qx * rn, qy * rn, qz * rn);
        out_l[n] = sl * inv;
    }
}

// ---------------- fallback path (R3) ----------------
__global__ void __launch_bounds__(256)
scatter_kernel(const int* __restrict__ dst, int* __restrict__ cnt,
               int* __restrict__ bucket, int cap,
               const float* __restrict__ node_levels, const float4* __restrict__ node_q,
               const float4* __restrict__ edge_rel_q, const float* __restrict__ edge_w,
               const int* __restrict__ src, float* __restrict__ side, int E) {
    int e = blockIdx.x * blockDim.x + threadIdx.x;
    if (e >= E) return;
    int d = dst[e];
    int slot = atomicAdd(&cnt[d], 1);
    if (slot < cap) {
        bucket[(long long)d * cap + slot] = e;
    } else {
        int s = src[e];
        float l = node_levels[s];
        float p = __expf(TEMP * edge_w[e] * l);
        float ow, ox, oy, oz;
        hamilton(edge_rel_q[e], node_q[s], ow, ox, oy, oz);
        float* rec = side + 6 * (long long)d;
        pk_fadd(rec + 0, p,      p * l);
        pk_fadd(rec + 2, p * ow, p * ox);
        pk_fadd(rec + 4, p * oy, p * oz);
    }
}

__global__ void __launch_bounds__(256)
gather_kernel(const float* __restrict__ node_levels, const float4* __restrict__ node_q,
              const float4* __restrict__ edge_rel_q, const float* __restrict__ edge_w,
              const int* __restrict__ src, const int* __restrict__ cnt,
              const int* __restrict__ bucket, int cap, const float* __restrict__ side,
              float4* __restrict__ out_q, float* __restrict__ out_l, int N) {
    int tid  = blockIdx.x * blockDim.x + threadIdx.x;
    int wave = tid >> 6, lane = tid & 63, half = lane >> 5, sub = lane & 31;
    int n = wave * 2 + half;
    float aZ = 0.f, aL = 0.f, a0 = 0.f, a1 = 0.f, a2 = 0.f, a3 = 0.f;
    if (n < N) {
        int deg = cnt[n]; if (deg > cap) deg = cap;
        const int* bkt = bucket + (long long)n * cap;
        for (int s = sub; s < deg; s += 32) {
            int e = bkt[s];
            int sn = src[e];
            float l = node_levels[sn];
            float p = __expf(TEMP * edge_w[e] * l);
            float ow, ox, oy, oz;
            hamilton(edge_rel_q[e], node_q[sn], ow, ox, oy, oz);
            aZ += p; aL += p * l; a0 += p * ow; a1 += p * ox; a2 += p * oy; a3 += p * oz;
        }
    }
    for (int m = 16; m; m >>= 1) {
        aZ += __shfl_xor(aZ, m); aL += __shfl_xor(aL, m);
        a0 += __shfl_xor(a0, m); a1 += __shfl_xor(a1, m);
        a2 += __shfl_xor(a2, m); a3 += __shfl_xor(a3, m);
    }
    if (sub == 0 && n < N) {
        const float* rec = side + 6 * (long long)n;
        float l  = node_levels[n];
        float ps = __expf(TEMP * l);
        float Z  = aZ + rec[0] + ps;
        float sl = aL + rec[1] + ps * l;
        float4 q = node_q[n];
        float qw = a0 + rec[2] + ps * q.x;
        float qx = a1 + rec[3] + ps * q.y;
        float qy = a2 + rec[4] + ps * q.z;
        float qz = a3 + rec[5] + ps * q.w;
        float inv = 1.0f / Z;
        qw *= inv; qx *= inv; qy *= inv; qz *= inv;
        float norm = fmaxf(sqrtf(qw*qw + qx*qx + qy*qy + qz*qz), 1e-12f);
        float rn = 1.0f / norm;
        out_q[n] = make_float4(qw * rn, qx * rn, qy * rn, qz * rn);
        out_l[n] = sl * inv;
    }
}

extern "C" void kernel_launch(void* const* d_in, const int* in_sizes, int n_in,
                              void* d_out, int out_size, void* d_ws, size_t ws_size,
                              hipStream_t stream) {
    const float*  node_levels = (const float*)d_in[0];
    const float4* node_q      = (const float4*)d_in[1];
    const float4* edge_rel_q  = (const float4*)d_in[2];
    const float*  edge_w      = (const float*)d_in[3];
    const int*    src         = (const int*)d_in[4];
    const int*    dst         = (const int*)d_in[5];

    const int N = in_sizes[0];
    const int E = in_sizes[3];

    const int B = (N + GSZ - 1) / GSZ;            // coarse buckets

    // pick largest scatter/hist grid that fits ws
    // ws layout: blkhist[B*NBLK] u32 | totals[B] | offsets[B+1] | pad | buckets[E] uint4
    int nblk = 0;
    size_t buckets_byte = 0;
    for (int nb : {1024, 768, 512, 384, 256}) {
        size_t head_elems = (size_t)B * nb + B + (B + 1);
        size_t hb = (head_elems * 4 + 15) & ~(size_t)15;
        if (hb + (size_t)E * 16 <= ws_size) { nblk = nb; buckets_byte = hb; break; }
    }

    if (nblk && B <= 1024 && (size_t)B * 4 <= 65536) {
        unsigned* blkhist = (unsigned*)d_ws;
        unsigned* totals  = blkhist + (size_t)B * nblk;
        unsigned* offsets = totals + B;
        uint4*    buckets = (uint4*)((char*)d_ws + buckets_byte);

        const int span = (E + nblk - 1) / nblk;

        hist_kernel<<<nblk, TPB, B * 4, stream>>>(dst, blkhist, E, B, span);
        scan_blocks_kernel<<<B, nblk, 0, stream>>>(blkhist, totals);
        scan_totals_kernel<<<1, 1024, 0, stream>>>(totals, offsets, B);
        scatter_pay_kernel<<<nblk, TPB, B * 4, stream>>>(
            node_levels, node_q, edge_rel_q, edge_w, src, dst,
            blkhist, offsets, buckets, E, B, span);
        gather_pay_kernel<<<B, TPB, 0, stream>>>(
            node_levels, node_q, offsets, buckets,
            (float4*)d_out, (float*)d_out + 4 * (long long)N, N);
    } else {
        // R3 fallback
        const int tpb = 256;
        size_t cnt_elems  = ((size_t)N + 3) & ~(size_t)3;
        size_t side_elems = 6 * (size_t)N;
        size_t head_bytes = (cnt_elems + side_elems) * 4;
        int cap = 0;
        for (int c : {128, 64}) {
            if (head_bytes + (size_t)N * c * 4 <= ws_size) { cap = c; break; }
        }
        int*   cnt    = (int*)d_ws;
        float* side   = (float*)d_ws + cnt_elems;
        int*   bucket = (int*)d_ws + cnt_elems + side_elems;
        hipMemsetAsync(d_ws, 0, head_bytes, stream);
        scatter_kernel<<<(E + tpb - 1) / tpb, tpb, 0, stream>>>(
            dst, cnt, bucket, cap, node_levels, node_q, edge_rel_q, edge_w, src, side, E);
        int waves  = (N + 1) / 2;
        int blocks = (waves * 64 + tpb - 1) / tpb;
        gather_kernel<<<blocks, tpb, 0, stream>>>(
            node_levels, node_q, edge_rel_q, edge_w, src, cnt, bucket, cap, side,
            (float4*)d_out, (float*)d_out + 4 * (long long)N, N);
    }
}

// Round 6
// 373.830 us; speedup vs baseline: 1.0605x; 1.0605x over previous
//
#include <hip/hip_runtime.h>
#include <hip/hip_fp16.h>

#define TEMP 10.0f
#define TPB 256
#define GTPB 512          // gather block size
#define NBLK 256          // hist/scatter grid
#define SHIFT 8
#define GSZ 256           // nodes per bucket = 1<<SHIFT

typedef float v2f  __attribute__((ext_vector_type(2)));
typedef float vf4  __attribute__((ext_vector_type(4)));
typedef unsigned uv4 __attribute__((ext_vector_type(4)));

__device__ __forceinline__ int   nt_i (const int* p)   { return __builtin_nontemporal_load(p); }
__device__ __forceinline__ float nt_f (const float* p) { return __builtin_nontemporal_load(p); }
__device__ __forceinline__ float4 nt_f4(const float4* p) {
    vf4 v = __builtin_nontemporal_load((const vf4*)p);
    return make_float4(v.x, v.y, v.z, v.w);
}
__device__ __forceinline__ uint4 nt_u4(const uint4* p) {
    uv4 v = __builtin_nontemporal_load((const uv4*)p);
    uint4 r; r.x = v.x; r.y = v.y; r.z = v.z; r.w = v.w; return r;
}

__device__ __forceinline__ void pk_fadd(float* p, float a, float b) {
#if __has_builtin(__builtin_amdgcn_global_atomic_fadd_v2f32)
    v2f v; v.x = a; v.y = b;
    __builtin_amdgcn_global_atomic_fadd_v2f32(
        (__attribute__((address_space(1))) v2f*)p, v);
#else
    atomicAdd(p, a); atomicAdd(p + 1, b);
#endif
}

__device__ __forceinline__ void hamilton(float4 a, float4 b,
                                         float& ow, float& ox, float& oy, float& oz) {
    ow = a.x*b.x - a.y*b.y - a.z*b.z - a.w*b.w;
    ox = a.x*b.y + a.y*b.x + a.z*b.w - a.w*b.z;
    oy = a.x*b.z - a.y*b.w + a.z*b.x + a.w*b.y;
    oz = a.x*b.w + a.y*b.z - a.z*b.y + a.w*b.x;
}

__device__ __forceinline__ unsigned f2h(float x) {
    return (unsigned)__half_as_ushort(__float2half_rn(x));
}
__device__ __forceinline__ float h2f(unsigned u) {
    return __half2float(__ushort_as_half((unsigned short)(u & 0xFFFFu)));
}

// ---------- pass H: per-block LDS histogram of dst buckets ----------
__global__ void __launch_bounds__(TPB)
hist_kernel(const int* __restrict__ dst, unsigned* __restrict__ blkhist,
            int E, int B, int span) {
    extern __shared__ unsigned h[];
    for (int i = threadIdx.x; i < B; i += blockDim.x) h[i] = 0;
    __syncthreads();
    int start = blockIdx.x * span;
    int end = start + span; if (end > E) end = E;
    for (int e = start + threadIdx.x; e < end; e += blockDim.x)
        atomicAdd(&h[((unsigned)nt_i(&dst[e])) >> SHIFT], 1u);
    __syncthreads();
    for (int i = threadIdx.x; i < B; i += blockDim.x)
        blkhist[(size_t)i * gridDim.x + blockIdx.x] = h[i];  // bucket-major
}

// ---------- pass P1: exclusive scan across blocks, per bucket ----------
__global__ void __launch_bounds__(NBLK)
scan_blocks_kernel(unsigned* __restrict__ blkhist, unsigned* __restrict__ totals) {
    __shared__ unsigned s[NBLK];
    int b = blockIdx.x, t = threadIdx.x;
    unsigned v = blkhist[(size_t)b * NBLK + t];
    s[t] = v; __syncthreads();
    for (int off = 1; off < NBLK; off <<= 1) {
        unsigned add = (t >= off) ? s[t - off] : 0u;
        __syncthreads();
        s[t] += add;
        __syncthreads();
    }
    blkhist[(size_t)b * NBLK + t] = s[t] - v;   // exclusive (local base)
    if (t == NBLK - 1) totals[b] = s[t];
}

// ---------- pass P2: exclusive scan of bucket totals ----------
__global__ void __launch_bounds__(1024)
scan_totals_kernel(const unsigned* __restrict__ totals,
                   unsigned* __restrict__ offsets, int B) {
    __shared__ unsigned s[1024];
    int t = threadIdx.x;
    unsigned v = (t < B) ? totals[t] : 0u;
    s[t] = v; __syncthreads();
    for (int off = 1; off < 1024; off <<= 1) {
        unsigned add = (t >= off) ? s[t - off] : 0u;
        __syncthreads();
        s[t] += add;
        __syncthreads();
    }
    if (t < B) offsets[t] = s[t] - v;
    if (t == B - 1) offsets[B] = s[t];
}

// ---------- pass S: compute payload, place at exact slot (no global atomics) ----------
__global__ void __launch_bounds__(TPB)
scatter_pay_kernel(const float* __restrict__ nl, const float4* __restrict__ nq,
                   const float4* __restrict__ erq, const float* __restrict__ ew,
                   const int* __restrict__ src, const int* __restrict__ dst,
                   const unsigned* __restrict__ blkhist,
                   const unsigned* __restrict__ offsets,
                   uint4* __restrict__ buckets,
                   int E, int B, int span) {
    extern __shared__ unsigned cur[];
    int blk = blockIdx.x, nb = gridDim.x;
    for (int b = threadIdx.x; b < B; b += blockDim.x)
        cur[b] = offsets[b] + blkhist[(size_t)b * nb + blk];
    __syncthreads();
    int start = blk * span;
    int end = start + span; if (end > E) end = E;
    for (int e = start + threadIdx.x; e < end; e += blockDim.x) {
        int s_ = nt_i(&src[e]);
        unsigned d = (unsigned)nt_i(&dst[e]);
        float l = nl[s_];
        float p = __expf(TEMP * nt_f(&ew[e]) * l);
        float ow, ox, oy, oz;
        hamilton(nt_f4(&erq[e]), nq[s_], ow, ox, oy, oz);
        unsigned slot = atomicAdd(&cur[d >> SHIFT], 1u);  // LDS cursor
        uint4 pk;
        pk.x = (d & (GSZ - 1)) | (f2h(p) << 16);
        pk.y = f2h(p * l)  | (f2h(p * ow) << 16);
        pk.z = f2h(p * ox) | (f2h(p * oy) << 16);
        pk.w = f2h(p * oz);
        buckets[slot] = pk;                                // normal store: wants L2 residency
    }
}

// ---------- pass G: per-bucket LDS accumulate + finalize ----------
__global__ void __launch_bounds__(GTPB)
gather_pay_kernel(const float* __restrict__ nl, const float4* __restrict__ nq,
                  const unsigned* __restrict__ offsets,
                  const uint4* __restrict__ buckets,
                  float4* __restrict__ out_q, float* __restrict__ out_l, int N) {
    __shared__ float acc[2][GSZ * 7];              // 2 copies: even/odd waves
    int b = blockIdx.x;
    for (int i = threadIdx.x; i < GSZ * 7; i += blockDim.x) {
        acc[0][i] = 0.f; acc[1][i] = 0.f;
    }
    __syncthreads();
    int copy = (threadIdx.x >> 6) & 1;
    unsigned s0 = offsets[b], s1 = offsets[b + 1];
    for (unsigned i = s0 + threadIdx.x; i < s1; i += blockDim.x) {
        uint4 pk = nt_u4(&buckets[i]);
        unsigned dl = pk.x & 0xFFFFu;
        float p  = h2f(pk.x >> 16);
        float pl = h2f(pk.y);
        float q0 = h2f(pk.y >> 16);
        float q1 = h2f(pk.z);
        float q2 = h2f(pk.z >> 16);
        float q3 = h2f(pk.w);
        float* a = &acc[copy][dl * 7];
        atomicAdd(a + 0, p);  atomicAdd(a + 1, pl);
        atomicAdd(a + 2, q0); atomicAdd(a + 3, q1);
        atomicAdd(a + 4, q2); atomicAdd(a + 5, q3);
    }
    __syncthreads();
    int n0 = b * GSZ;
    for (int j = threadIdx.x; j < GSZ; j += blockDim.x) {
        int n = n0 + j;
        if (n >= N) break;
        float l = nl[n];
        float ps = __expf(TEMP * l);
        const float* a0 = &acc[0][j * 7];
        const float* a1 = &acc[1][j * 7];
        float Z  = a0[0] + a1[0] + ps;
        float sl = a0[1] + a1[1] + ps * l;
        float4 q = nq[n];
        float qw = a0[2] + a1[2] + ps * q.x;
        float qx = a0[3] + a1[3] + ps * q.y;
        float qy = a0[4] + a1[4] + ps * q.z;
        float qz = a0[5] + a1[5] + ps * q.w;
        float inv = 1.0f / Z;
        qw *= inv; qx *= inv; qy *= inv; qz *= inv;
        float norm = fmaxf(sqrtf(qw*qw + qx*qx + qy*qy + qz*qz), 1e-12f);
        float rn = 1.0f / norm;
        out_q[n] = make_float4(qw * rn, qx * rn, qy * rn, qz * rn);
        out_l[n] = sl * inv;
    }
}

// ---------------- fallback path (R3) ----------------
__global__ void __launch_bounds__(256)
scatter_kernel(const int* __restrict__ dst, int* __restrict__ cnt,
               int* __restrict__ bucket, int cap,
               const float* __restrict__ node_levels, const float4* __restrict__ node_q,
               const float4* __restrict__ edge_rel_q, const float* __restrict__ edge_w,
               const int* __restrict__ src, float* __restrict__ side, int E) {
    int e = blockIdx.x * blockDim.x + threadIdx.x;
    if (e >= E) return;
    int d = dst[e];
    int slot = atomicAdd(&cnt[d], 1);
    if (slot < cap) {
        bucket[(long long)d * cap + slot] = e;
    } else {
        int s = src[e];
        float l = node_levels[s];
        float p = __expf(TEMP * edge_w[e] * l);
        float ow, ox, oy, oz;
        hamilton(edge_rel_q[e], node_q[s], ow, ox, oy, oz);
        float* rec = side + 6 * (long long)d;
        pk_fadd(rec + 0, p,      p * l);
        pk_fadd(rec + 2, p * ow, p * ox);
        pk_fadd(rec + 4, p * oy, p * oz);
    }
}

__global__ void __launch_bounds__(256)
gather_kernel(const float* __restrict__ node_levels, const float4* __restrict__ node_q,
              const float4* __restrict__ edge_rel_q, const float* __restrict__ edge_w,
              const int* __restrict__ src, const int* __restrict__ cnt,
              const int* __restrict__ bucket, int cap, const float* __restrict__ side,
              float4* __restrict__ out_q, float* __restrict__ out_l, int N) {
    int tid  = blockIdx.x * blockDim.x + threadIdx.x;
    int wave = tid >> 6, lane = tid & 63, half = lane >> 5, sub = lane & 31;
    int n = wave * 2 + half;
    float aZ = 0.f, aL = 0.f, a0 = 0.f, a1 = 0.f, a2 = 0.f, a3 = 0.f;
    if (n < N) {
        int deg = cnt[n]; if (deg > cap) deg = cap;
        const int* bkt = bucket + (long long)n * cap;
        for (int s = sub; s < deg; s += 32) {
            int e = bkt[s];
            int sn = src[e];
            float l = node_levels[sn];
            float p = __expf(TEMP * edge_w[e] * l);
            float ow, ox, oy, oz;
            hamilton(edge_rel_q[e], node_q[sn], ow, ox, oy, oz);
            aZ += p; aL += p * l; a0 += p * ow; a1 += p * ox; a2 += p * oy; a3 += p * oz;
        }
    }
    for (int m = 16; m; m >>= 1) {
        aZ += __shfl_xor(aZ, m); aL += __shfl_xor(aL, m);
        a0 += __shfl_xor(a0, m); a1 += __shfl_xor(a1, m);
        a2 += __shfl_xor(a2, m); a3 += __shfl_xor(a3, m);
    }
    if (sub == 0 && n < N) {
        const float* rec = side + 6 * (long long)n;
        float l  = node_levels[n];
        float ps = __expf(TEMP * l);
        float Z  = aZ + rec[0] + ps;
        float sl = aL + rec[1] + ps * l;
        float4 q = node_q[n];
        float qw = a0 + rec[2] + ps * q.x;
        float qx = a1 + rec[3] + ps * q.y;
        float qy = a2 + rec[4] + ps * q.z;
        float qz = a3 + rec[5] + ps * q.w;
        float inv = 1.0f / Z;
        qw *= inv; qx *= inv; qy *= inv; qz *= inv;
        float norm = fmaxf(sqrtf(qw*qw + qx*qx + qy*qy + qz*qz), 1e-12f);
        float rn = 1.0f / norm;
        out_q[n] = make_float4(qw * rn, qx * rn, qy * rn, qz * rn);
        out_l[n] = sl * inv;
    }
}

extern "C" void kernel_launch(void* const* d_in, const int* in_sizes, int n_in,
                              void* d_out, int out_size, void* d_ws, size_t ws_size,
                              hipStream_t stream) {
    const float*  node_levels = (const float*)d_in[0];
    const float4* node_q      = (const float4*)d_in[1];
    const float4* edge_rel_q  = (const float4*)d_in[2];
    const float*  edge_w      = (const float*)d_in[3];
    const int*    src         = (const int*)d_in[4];
    const int*    dst         = (const int*)d_in[5];

    const int N = in_sizes[0];
    const int E = in_sizes[3];

    const int B = (N + GSZ - 1) / GSZ;            // coarse buckets
    const int span = (E + NBLK - 1) / NBLK;

    // ws layout: blkhist[B*NBLK] u32 | totals[B] | offsets[B+1] | pad | buckets[E] uint4
    size_t head_elems   = (size_t)B * NBLK + B + (B + 1);
    size_t buckets_byte = (head_elems * 4 + 15) & ~(size_t)15;
    size_t need         = buckets_byte + (size_t)E * 16;

    if (need <= ws_size && B <= 1024 && (size_t)B * 4 <= 65536) {
        unsigned* blkhist = (unsigned*)d_ws;
        unsigned* totals  = blkhist + (size_t)B * NBLK;
        unsigned* offsets = totals + B;
        uint4*    buckets = (uint4*)((char*)d_ws + buckets_byte);

        hist_kernel<<<NBLK, TPB, B * 4, stream>>>(dst, blkhist, E, B, span);
        scan_blocks_kernel<<<B, NBLK, 0, stream>>>(blkhist, totals);
        scan_totals_kernel<<<1, 1024, 0, stream>>>(totals, offsets, B);
        scatter_pay_kernel<<<NBLK, TPB, B * 4, stream>>>(
            node_levels, node_q, edge_rel_q, edge_w, src, dst,
            blkhist, offsets, buckets, E, B, span);
        gather_pay_kernel<<<B, GTPB, 0, stream>>>(
            node_levels, node_q, offsets, buckets,
            (float4*)d_out, (float*)d_out + 4 * (long long)N, N);
    } else {
        // R3 fallback
        const int tpb = 256;
        size_t cnt_elems  = ((size_t)N + 3) & ~(size_t)3;
        size_t side_elems = 6 * (size_t)N;
        size_t head_bytes = (cnt_elems + side_elems) * 4;
        int cap = 0;
        for (int c : {128, 64}) {
            if (head_bytes + (size_t)N * c * 4 <= ws_size) { cap = c; break; }
        }
        int*   cnt    = (int*)d_ws;
        float* side   = (float*)d_ws + cnt_elems;
        int*   bucket = (int*)d_ws + cnt_elems + side_elems;
        hipMemsetAsync(d_ws, 0, head_bytes, stream);
        scatter_kernel<<<(E + tpb - 1) / tpb, tpb, 0, stream>>>(
            dst, cnt, bucket, cap, node_levels, node_q, edge_rel_q, edge_w, src, side, E);
        int waves  = (N + 1) / 2;
        int blocks = (waves * 64 + tpb - 1) / tpb;
        gather_kernel<<<blocks, tpb, 0, stream>>>(
            node_levels, node_q, edge_rel_q, edge_w, src, cnt, bucket, cap, side,
            (float4*)d_out, (float*)d_out + 4 * (long long)N, N);
    }
}

// Round 7
// 290.502 us; speedup vs baseline: 1.3646x; 1.2868x over previous
//
#include <hip/hip_runtime.h>
#include <hip/hip_fp16.h>

#define TEMP 10.0f
#define TPB 256
#define NBLK 256          // hist/scatter grid
#define SHIFT 8
#define GSZ 256           // nodes per bucket = 1<<SHIFT
#define GTPB 1024         // gather block size
#define CAP 64            // per-node slot capacity in gather (overflow handled)

typedef float v2f  __attribute__((ext_vector_type(2)));
typedef float vf4  __attribute__((ext_vector_type(4)));
typedef unsigned uv4 __attribute__((ext_vector_type(4)));

__device__ __forceinline__ int   nt_i (const int* p)   { return __builtin_nontemporal_load(p); }
__device__ __forceinline__ float nt_f (const float* p) { return __builtin_nontemporal_load(p); }
__device__ __forceinline__ float4 nt_f4(const float4* p) {
    vf4 v = __builtin_nontemporal_load((const vf4*)p);
    return make_float4(v.x, v.y, v.z, v.w);
}
__device__ __forceinline__ uint4 nt_u4(const uint4* p) {
    uv4 v = __builtin_nontemporal_load((const uv4*)p);
    uint4 r; r.x = v.x; r.y = v.y; r.z = v.z; r.w = v.w; return r;
}

__device__ __forceinline__ void pk_fadd(float* p, float a, float b) {
#if __has_builtin(__builtin_amdgcn_global_atomic_fadd_v2f32)
    v2f v; v.x = a; v.y = b;
    __builtin_amdgcn_global_atomic_fadd_v2f32(
        (__attribute__((address_space(1))) v2f*)p, v);
#else
    atomicAdd(p, a); atomicAdd(p + 1, b);
#endif
}

__device__ __forceinline__ void hamilton(float4 a, float4 b,
                                         float& ow, float& ox, float& oy, float& oz) {
    ow = a.x*b.x - a.y*b.y - a.z*b.z - a.w*b.w;
    ox = a.x*b.y + a.y*b.x + a.z*b.w - a.w*b.z;
    oy = a.x*b.z - a.y*b.w + a.z*b.x + a.w*b.y;
    oz = a.x*b.w + a.y*b.z - a.z*b.y + a.w*b.x;
}

__device__ __forceinline__ unsigned f2h(float x) {
    return (unsigned)__half_as_ushort(__float2half_rn(x));
}
__device__ __forceinline__ float h2f(unsigned u) {
    return __half2float(__ushort_as_half((unsigned short)(u & 0xFFFFu)));
}

// ---------- pass H: per-block LDS histogram of dst buckets ----------
__global__ void __launch_bounds__(TPB)
hist_kernel(const int* __restrict__ dst, unsigned* __restrict__ blkhist,
            int E, int B, int span) {
    extern __shared__ unsigned h[];
    for (int i = threadIdx.x; i < B; i += blockDim.x) h[i] = 0;
    __syncthreads();
    int start = blockIdx.x * span;
    int end = start + span; if (end > E) end = E;
    for (int e = start + threadIdx.x; e < end; e += blockDim.x)
        atomicAdd(&h[((unsigned)nt_i(&dst[e])) >> SHIFT], 1u);
    __syncthreads();
    for (int i = threadIdx.x; i < B; i += blockDim.x)
        blkhist[(size_t)i * gridDim.x + blockIdx.x] = h[i];  // bucket-major
}

// ---------- pass P1: exclusive scan across blocks, per bucket ----------
__global__ void __launch_bounds__(NBLK)
scan_blocks_kernel(unsigned* __restrict__ blkhist, unsigned* __restrict__ totals) {
    __shared__ unsigned s[NBLK];
    int b = blockIdx.x, t = threadIdx.x;
    unsigned v = blkhist[(size_t)b * NBLK + t];
    s[t] = v; __syncthreads();
    for (int off = 1; off < NBLK; off <<= 1) {
        unsigned add = (t >= off) ? s[t - off] : 0u;
        __syncthreads();
        s[t] += add;
        __syncthreads();
    }
    blkhist[(size_t)b * NBLK + t] = s[t] - v;   // exclusive (local base)
    if (t == NBLK - 1) totals[b] = s[t];
}

// ---------- pass P2: exclusive scan of bucket totals ----------
__global__ void __launch_bounds__(1024)
scan_totals_kernel(const unsigned* __restrict__ totals,
                   unsigned* __restrict__ offsets, int B) {
    __shared__ unsigned s[1024];
    int t = threadIdx.x;
    unsigned v = (t < B) ? totals[t] : 0u;
    s[t] = v; __syncthreads();
    for (int off = 1; off < 1024; off <<= 1) {
        unsigned add = (t >= off) ? s[t - off] : 0u;
        __syncthreads();
        s[t] += add;
        __syncthreads();
    }
    if (t < B) offsets[t] = s[t] - v;
    if (t == B - 1) offsets[B] = s[t];
}

// ---------- pass S: compute payload, place at exact slot (no global atomics) ----------
__global__ void __launch_bounds__(TPB)
scatter_pay_kernel(const float* __restrict__ nl, const float4* __restrict__ nq,
                   const float4* __restrict__ erq, const float* __restrict__ ew,
                   const int* __restrict__ src, const int* __restrict__ dst,
                   const unsigned* __restrict__ blkhist,
                   const unsigned* __restrict__ offsets,
                   uint4* __restrict__ buckets,
                   int E, int B, int span) {
    extern __shared__ unsigned cur[];
    int blk = blockIdx.x, nb = gridDim.x;
    for (int b = threadIdx.x; b < B; b += blockDim.x)
        cur[b] = offsets[b] + blkhist[(size_t)b * nb + blk];
    __syncthreads();
    int start = blk * span;
    int end = start + span; if (end > E) end = E;
    for (int e = start + threadIdx.x; e < end; e += blockDim.x) {
        int s_ = nt_i(&src[e]);
        unsigned d = (unsigned)nt_i(&dst[e]);
        float l = nl[s_];
        float p = __expf(TEMP * nt_f(&ew[e]) * l);
        float ow, ox, oy, oz;
        hamilton(nt_f4(&erq[e]), nq[s_], ow, ox, oy, oz);
        unsigned slot = atomicAdd(&cur[d >> SHIFT], 1u);  // LDS cursor
        uint4 pk;
        pk.x = (d & (GSZ - 1)) | (f2h(p) << 16);
        pk.y = f2h(p * l)  | (f2h(p * ow) << 16);
        pk.z = f2h(p * ox) | (f2h(p * oy) << 16);
        pk.w = f2h(p * oz);
        buckets[slot] = pk;                                // normal store: wants L2 residency
    }
}

// ---------- pass G: per-bucket counting-sort by node + register reduce ----------
__global__ void __launch_bounds__(GTPB)
gather_pay_kernel(const float* __restrict__ nl, const float4* __restrict__ nq,
                  const unsigned* __restrict__ offsets,
                  const uint4* __restrict__ buckets,
                  float4* __restrict__ out_q, float* __restrict__ out_l, int N) {
    __shared__ unsigned short idx[GSZ * CAP];   // 32 KB: per-node record lists
    __shared__ int   curn[GSZ];                 // per-node cursors
    __shared__ float ovf[GSZ * 7];              // overflow accumulator (rarely used)
    int b = blockIdx.x;
    for (int i = threadIdx.x; i < GSZ; i += blockDim.x) curn[i] = 0;
    for (int i = threadIdx.x; i < GSZ * 7; i += blockDim.x) ovf[i] = 0.f;
    __syncthreads();

    unsigned s0 = offsets[b], s1 = offsets[b + 1];
    int M = (int)(s1 - s0);
    const unsigned* bx = (const unsigned*)(buckets + s0);   // .x words at stride 4

    // phase 1: one LDS atomic per record -> per-node index lists
    for (int i = threadIdx.x; i < M; i += blockDim.x) {
        unsigned w0 = bx[4 * (size_t)i];
        unsigned dl = w0 & (GSZ - 1);
        int slot = atomicAdd(&curn[dl], 1);
        if (slot < CAP) {
            idx[dl * CAP + slot] = (unsigned short)i;
        } else {
            // overflow: accumulate directly (rare)
            uint4 pk = buckets[s0 + i];
            float* a = &ovf[dl * 7];
            atomicAdd(a + 0, h2f(pk.x >> 16));
            atomicAdd(a + 1, h2f(pk.y));
            atomicAdd(a + 2, h2f(pk.y >> 16));
            atomicAdd(a + 3, h2f(pk.z));
            atomicAdd(a + 4, h2f(pk.z >> 16));
            atomicAdd(a + 5, h2f(pk.w));
        }
    }
    __syncthreads();

    // phase 2: 4 threads per node walk the list, accumulate in registers
    int j = threadIdx.x >> 2;        // node within bucket
    int r = threadIdx.x & 3;
    int deg = curn[j]; if (deg > CAP) deg = CAP;
    float aZ = 0.f, aL = 0.f, a0 = 0.f, a1 = 0.f, a2 = 0.f, a3 = 0.f;
    for (int s = r; s < deg; s += 4) {
        int i = idx[j * CAP + s];
        uint4 pk = nt_u4(&buckets[s0 + i]);
        aZ += h2f(pk.x >> 16);
        aL += h2f(pk.y);
        a0 += h2f(pk.y >> 16);
        a1 += h2f(pk.z);
        a2 += h2f(pk.z >> 16);
        a3 += h2f(pk.w);
    }
    // combine 4 consecutive lanes (same wave)
    for (int m = 1; m <= 2; m <<= 1) {
        aZ += __shfl_xor(aZ, m); aL += __shfl_xor(aL, m);
        a0 += __shfl_xor(a0, m); a1 += __shfl_xor(a1, m);
        a2 += __shfl_xor(a2, m); a3 += __shfl_xor(a3, m);
    }
    if (r == 0) {
        int n = b * GSZ + j;
        if (n < N) {
            const float* o = &ovf[j * 7];
            float l = nl[n];
            float ps = __expf(TEMP * l);
            float Z  = aZ + o[0] + ps;
            float sl = aL + o[1] + ps * l;
            float4 q = nq[n];
            float qw = a0 + o[2] + ps * q.x;
            float qx = a1 + o[3] + ps * q.y;
            float qy = a2 + o[4] + ps * q.z;
            float qz = a3 + o[5] + ps * q.w;
            float inv = 1.0f / Z;
            qw *= inv; qx *= inv; qy *= inv; qz *= inv;
            float norm = fmaxf(sqrtf(qw*qw + qx*qx + qy*qy + qz*qz), 1e-12f);
            float rn = 1.0f / norm;
            out_q[n] = make_float4(qw * rn, qx * rn, qy * rn, qz * rn);
            out_l[n] = sl * inv;
        }
    }
}

// ---------------- fallback path (R3) ----------------
__global__ void __launch_bounds__(256)
scatter_kernel(const int* __restrict__ dst, int* __restrict__ cnt,
               int* __restrict__ bucket, int cap,
               const float* __restrict__ node_levels, const float4* __restrict__ node_q,
               const float4* __restrict__ edge_rel_q, const float* __restrict__ edge_w,
               const int* __restrict__ src, float* __restrict__ side, int E) {
    int e = blockIdx.x * blockDim.x + threadIdx.x;
    if (e >= E) return;
    int d = dst[e];
    int slot = atomicAdd(&cnt[d], 1);
    if (slot < cap) {
        bucket[(long long)d * cap + slot] = e;
    } else {
        int s = src[e];
        float l = node_levels[s];
        float p = __expf(TEMP * edge_w[e] * l);
        float ow, ox, oy, oz;
        hamilton(edge_rel_q[e], node_q[s], ow, ox, oy, oz);
        float* rec = side + 6 * (long long)d;
        pk_fadd(rec + 0, p,      p * l);
        pk_fadd(rec + 2, p * ow, p * ox);
        pk_fadd(rec + 4, p * oy, p * oz);
    }
}

__global__ void __launch_bounds__(256)
gather_kernel(const float* __restrict__ node_levels, const float4* __restrict__ node_q,
              const float4* __restrict__ edge_rel_q, const float* __restrict__ edge_w,
              const int* __restrict__ src, const int* __restrict__ cnt,
              const int* __restrict__ bucket, int cap, const float* __restrict__ side,
              float4* __restrict__ out_q, float* __restrict__ out_l, int N) {
    int tid  = blockIdx.x * blockDim.x + threadIdx.x;
    int wave = tid >> 6, lane = tid & 63, half = lane >> 5, sub = lane & 31;
    int n = wave * 2 + half;
    float aZ = 0.f, aL = 0.f, a0 = 0.f, a1 = 0.f, a2 = 0.f, a3 = 0.f;
    if (n < N) {
        int deg = cnt[n]; if (deg > cap) deg = cap;
        const int* bkt = bucket + (long long)n * cap;
        for (int s = sub; s < deg; s += 32) {
            int e = bkt[s];
            int sn = src[e];
            float l = node_levels[sn];
            float p = __expf(TEMP * edge_w[e] * l);
            float ow, ox, oy, oz;
            hamilton(edge_rel_q[e], node_q[sn], ow, ox, oy, oz);
            aZ += p; aL += p * l; a0 += p * ow; a1 += p * ox; a2 += p * oy; a3 += p * oz;
        }
    }
    for (int m = 16; m; m >>= 1) {
        aZ += __shfl_xor(aZ, m); aL += __shfl_xor(aL, m);
        a0 += __shfl_xor(a0, m); a1 += __shfl_xor(a1, m);
        a2 += __shfl_xor(a2, m); a3 += __shfl_xor(a3, m);
    }
    if (sub == 0 && n < N) {
        const float* rec = side + 6 * (long long)n;
        float l  = node_levels[n];
        float ps = __expf(TEMP * l);
        float Z  = aZ + rec[0] + ps;
        float sl = aL + rec[1] + ps * l;
        float4 q = node_q[n];
        float qw = a0 + rec[2] + ps * q.x;
        float qx = a1 + rec[3] + ps * q.y;
        float qy = a2 + rec[4] + ps * q.z;
        float qz = a3 + rec[5] + ps * q.w;
        float inv = 1.0f / Z;
        qw *= inv; qx *= inv; qy *= inv; qz *= inv;
        float norm = fmaxf(sqrtf(qw*qw + qx*qx + qy*qy + qz*qz), 1e-12f);
        float rn = 1.0f / norm;
        out_q[n] = make_float4(qw * rn, qx * rn, qy * rn, qz * rn);
        out_l[n] = sl * inv;
    }
}

extern "C" void kernel_launch(void* const* d_in, const int* in_sizes, int n_in,
                              void* d_out, int out_size, void* d_ws, size_t ws_size,
                              hipStream_t stream) {
    const float*  node_levels = (const float*)d_in[0];
    const float4* node_q      = (const float4*)d_in[1];
    const float4* edge_rel_q  = (const float4*)d_in[2];
    const float*  edge_w      = (const float*)d_in[3];
    const int*    src         = (const int*)d_in[4];
    const int*    dst         = (const int*)d_in[5];

    const int N = in_sizes[0];
    const int E = in_sizes[3];

    const int B = (N + GSZ - 1) / GSZ;            // coarse buckets
    const int span = (E + NBLK - 1) / NBLK;

    // ws layout: blkhist[B*NBLK] u32 | totals[B] | offsets[B+1] | pad | buckets[E] uint4
    size_t head_elems   = (size_t)B * NBLK + B + (B + 1);
    size_t buckets_byte = (head_elems * 4 + 15) & ~(size_t)15;
    size_t need         = buckets_byte + (size_t)E * 16;

    // gather's u16 idx requires bucket segments < 65536 records; with E/B ~ 8.2K
    // and Poisson spread this is safe by 7x, but guard structurally anyway.
    bool seg_ok = ((size_t)E / (size_t)B) < 32768;

    if (need <= ws_size && B <= 1024 && (size_t)B * 4 <= 65536 && seg_ok) {
        unsigned* blkhist = (unsigned*)d_ws;
        unsigned* totals  = blkhist + (size_t)B * NBLK;
        unsigned* offsets = totals + B;
        uint4*    buckets = (uint4*)((char*)d_ws + buckets_byte);

        hist_kernel<<<NBLK, TPB, B * 4, stream>>>(dst, blkhist, E, B, span);
        scan_blocks_kernel<<<B, NBLK, 0, stream>>>(blkhist, totals);
        scan_totals_kernel<<<1, 1024, 0, stream>>>(totals, offsets, B);
        scatter_pay_kernel<<<NBLK, TPB, B * 4, stream>>>(
            node_levels, node_q, edge_rel_q, edge_w, src, dst,
            blkhist, offsets, buckets, E, B, span);
        gather_pay_kernel<<<B, GTPB, 0, stream>>>(
            node_levels, node_q, offsets, buckets,
            (float4*)d_out, (float*)d_out + 4 * (long long)N, N);
    } else {
        // R3 fallback
        const int tpb = 256;
        size_t cnt_elems  = ((size_t)N + 3) & ~(size_t)3;
        size_t side_elems = 6 * (size_t)N;
        size_t head_bytes = (cnt_elems + side_elems) * 4;
        int cap = 0;
        for (int c : {128, 64}) {
            if (head_bytes + (size_t)N * c * 4 <= ws_size) { cap = c; break; }
        }
        int*   cnt    = (int*)d_ws;
        float* side   = (float*)d_ws + cnt_elems;
        int*   bucket = (int*)d_ws + cnt_elems + side_elems;
        hipMemsetAsync(d_ws, 0, head_bytes, stream);
        scatter_kernel<<<(E + tpb - 1) / tpb, tpb, 0, stream>>>(
            dst, cnt, bucket, cap, node_levels, node_q, edge_rel_q, edge_w, src, side, E);
        int waves  = (N + 1) / 2;
        int blocks = (waves * 64 + tpb - 1) / tpb;
        gather_kernel<<<blocks, tpb, 0, stream>>>(
            node_levels, node_q, edge_rel_q, edge_w, src, cnt, bucket, cap, side,
            (float4*)d_out, (float*)d_out + 4 * (long long)N, N);
    }
}

// Round 8
// 246.821 us; speedup vs baseline: 1.6061x; 1.1770x over previous
//
#include <hip/hip_runtime.h>
#include <hip/hip_fp16.h>

#define TEMP 10.0f
#define TPB 256
#define NBLK 512          // hist/scatter grid
#define SHIFT 9
#define GSZ 512           // nodes per bucket = 1<<SHIFT
#define BMAX 256          // max buckets supported by scatter LDS arrays
#define TILE 2048         // edges per scatter tile
#define GTPB 1024         // gather block size
#define CAP 44            // per-node slot capacity in gather (overflow handled)

typedef float v2f  __attribute__((ext_vector_type(2)));
typedef float vf4  __attribute__((ext_vector_type(4)));
typedef unsigned uv4 __attribute__((ext_vector_type(4)));

__device__ __forceinline__ int   nt_i (const int* p)   { return __builtin_nontemporal_load(p); }
__device__ __forceinline__ float nt_f (const float* p) { return __builtin_nontemporal_load(p); }
__device__ __forceinline__ float4 nt_f4(const float4* p) {
    vf4 v = __builtin_nontemporal_load((const vf4*)p);
    return make_float4(v.x, v.y, v.z, v.w);
}
__device__ __forceinline__ uint4 nt_u4(const uint4* p) {
    uv4 v = __builtin_nontemporal_load((const uv4*)p);
    uint4 r; r.x = v.x; r.y = v.y; r.z = v.z; r.w = v.w; return r;
}

__device__ __forceinline__ void pk_fadd(float* p, float a, float b) {
#if __has_builtin(__builtin_amdgcn_global_atomic_fadd_v2f32)
    v2f v; v.x = a; v.y = b;
    __builtin_amdgcn_global_atomic_fadd_v2f32(
        (__attribute__((address_space(1))) v2f*)p, v);
#else
    atomicAdd(p, a); atomicAdd(p + 1, b);
#endif
}

__device__ __forceinline__ void hamilton(float4 a, float4 b,
                                         float& ow, float& ox, float& oy, float& oz) {
    ow = a.x*b.x - a.y*b.y - a.z*b.z - a.w*b.w;
    ox = a.x*b.y + a.y*b.x + a.z*b.w - a.w*b.z;
    oy = a.x*b.z - a.y*b.w + a.z*b.x + a.w*b.y;
    oz = a.x*b.w + a.y*b.z - a.z*b.y + a.w*b.x;
}

__device__ __forceinline__ unsigned f2h(float x) {
    return (unsigned)__half_as_ushort(__float2half_rn(x));
}
__device__ __forceinline__ float h2f(unsigned u) {
    return __half2float(__ushort_as_half((unsigned short)(u & 0xFFFFu)));
}

// ---------- pass H: per-block LDS histogram of dst buckets ----------
__global__ void __launch_bounds__(TPB)
hist_kernel(const int* __restrict__ dst, unsigned* __restrict__ blkhist,
            int E, int B, int span) {
    extern __shared__ unsigned h[];
    for (int i = threadIdx.x; i < B; i += blockDim.x) h[i] = 0;
    __syncthreads();
    int start = blockIdx.x * span;
    int end = start + span; if (end > E) end = E;
    for (int e = start + threadIdx.x; e < end; e += blockDim.x)
        atomicAdd(&h[((unsigned)nt_i(&dst[e])) >> SHIFT], 1u);
    __syncthreads();
    for (int i = threadIdx.x; i < B; i += blockDim.x)
        blkhist[(size_t)i * gridDim.x + blockIdx.x] = h[i];  // bucket-major
}

// ---------- pass P1: exclusive scan across blocks, per bucket ----------
__global__ void __launch_bounds__(1024)
scan_blocks_kernel(unsigned* __restrict__ blkhist, unsigned* __restrict__ totals) {
    __shared__ unsigned s[1024];
    int b = blockIdx.x, t = threadIdx.x, n = blockDim.x;
    unsigned v = blkhist[(size_t)b * n + t];
    s[t] = v; __syncthreads();
    for (int off = 1; off < n; off <<= 1) {
        unsigned add = (t >= off) ? s[t - off] : 0u;
        __syncthreads();
        s[t] += add;
        __syncthreads();
    }
    blkhist[(size_t)b * n + t] = s[t] - v;   // exclusive (local base)
    if (t == n - 1) totals[b] = s[t];
}

// ---------- pass P2: exclusive scan of bucket totals ----------
__global__ void __launch_bounds__(1024)
scan_totals_kernel(const unsigned* __restrict__ totals,
                   unsigned* __restrict__ offsets, int B) {
    __shared__ unsigned s[1024];
    int t = threadIdx.x;
    unsigned v = (t < B) ? totals[t] : 0u;
    s[t] = v; __syncthreads();
    for (int off = 1; off < 1024; off <<= 1) {
        unsigned add = (t >= off) ? s[t - off] : 0u;
        __syncthreads();
        s[t] += add;
        __syncthreads();
    }
    if (t < B) offsets[t] = s[t] - v;
    if (t == B - 1) offsets[B] = s[t];
}

// ---------- pass S: tile-sorted payload placement (no global atomics) ----------
__global__ void __launch_bounds__(TPB)
scatter_sort_kernel(const float* __restrict__ nl, const float4* __restrict__ nq,
                    const float4* __restrict__ erq, const float* __restrict__ ew,
                    const int* __restrict__ src, const int* __restrict__ dst,
                    const unsigned* __restrict__ blkhist,
                    const unsigned* __restrict__ offsets,
                    uint4* __restrict__ buckets,
                    int E, int B, int span) {
    __shared__ uint4    stage[TILE];     // 32 KB
    __shared__ unsigned gslot[TILE];     //  8 KB
    __shared__ unsigned gcur[BMAX];
    __shared__ unsigned th[BMAX];
    __shared__ unsigned sA[TPB];
    __shared__ unsigned basec[BMAX];
    __shared__ unsigned curt[BMAX];

    int blk = blockIdx.x, nb = gridDim.x, tid = threadIdx.x;
    for (int b = tid; b < B; b += TPB)
        gcur[b] = offsets[b] + blkhist[(size_t)b * nb + blk];
    int start = blk * span;
    int end = start + span; if (end > E) end = E;

    for (int ts = start; ts < end; ts += TILE) {
        int tE = end - ts; if (tE > TILE) tE = TILE;
        for (int b = tid; b < B; b += TPB) th[b] = 0;
        __syncthreads();
        // tile histogram
        for (int k = tid; k < tE; k += TPB)
            atomicAdd(&th[((unsigned)dst[ts + k]) >> SHIFT], 1u);
        __syncthreads();
        // exclusive scan over B buckets (B <= TPB)
        unsigned c = (tid < B) ? th[tid] : 0u;
        sA[tid] = c; __syncthreads();
        for (int off = 1; off < TPB; off <<= 1) {
            unsigned add = (tid >= off) ? sA[tid - off] : 0u;
            __syncthreads();
            sA[tid] += add;
            __syncthreads();
        }
        if (tid < B) { basec[tid] = sA[tid] - c; curt[tid] = sA[tid] - c; }
        __syncthreads();
        // compute payloads, place bucket-sorted into LDS stage
        for (int k = tid; k < tE; k += TPB) {
            int e = ts + k;
            int s_ = nt_i(&src[e]);
            unsigned d = (unsigned)dst[e];
            float l = nl[s_];
            float p = __expf(TEMP * nt_f(&ew[e]) * l);
            float ow, ox, oy, oz;
            hamilton(nt_f4(&erq[e]), nq[s_], ow, ox, oy, oz);
            unsigned b = d >> SHIFT;
            unsigned pos = atomicAdd(&curt[b], 1u);
            uint4 pk;
            pk.x = (d & (GSZ - 1)) | (f2h(p) << 16);
            pk.y = f2h(p * l)  | (f2h(p * ow) << 16);
            pk.z = f2h(p * ox) | (f2h(p * oy) << 16);
            pk.w = f2h(p * oz);
            stage[pos] = pk;
            gslot[pos] = gcur[b] + (pos - basec[b]);
        }
        __syncthreads();
        // flush in sorted order: consecutive lanes -> consecutive slots
        for (int k = tid; k < tE; k += TPB)
            buckets[gslot[k]] = stage[k];
        __syncthreads();
        for (int b = tid; b < B; b += TPB) gcur[b] += th[b];
        __syncthreads();
    }
}

// ---------- pass G: per-bucket counting-sort by node + register reduce ----------
__global__ void __launch_bounds__(GTPB)
gather_pay_kernel(const float* __restrict__ nl, const float4* __restrict__ nq,
                  const unsigned* __restrict__ offsets,
                  const uint4* __restrict__ buckets,
                  float4* __restrict__ out_q, float* __restrict__ out_l, int N) {
    __shared__ unsigned short idx[GSZ * CAP];   // 45 KB
    __shared__ int   curn[GSZ];                 //  2 KB
    __shared__ float ovf[GSZ * 7];              // 14 KB
    int b = blockIdx.x, tid = threadIdx.x;
    for (int i = tid; i < GSZ; i += GTPB) curn[i] = 0;
    for (int i = tid; i < GSZ * 7; i += GTPB) ovf[i] = 0.f;
    __syncthreads();

    unsigned s0 = offsets[b], s1 = offsets[b + 1];
    int M = (int)(s1 - s0);
    const unsigned* bx = (const unsigned*)(buckets + s0);

    // phase 1: one LDS atomic per record -> per-node index lists
    for (int i = tid; i < M; i += GTPB) {
        unsigned w0 = bx[4 * (size_t)i];
        unsigned dl = w0 & (GSZ - 1);
        int slot = atomicAdd(&curn[dl], 1);
        if (slot < CAP) {
            idx[dl * CAP + slot] = (unsigned short)i;
        } else {
            uint4 pk = buckets[s0 + i];
            float* a = &ovf[dl * 7];
            atomicAdd(a + 0, h2f(pk.x >> 16));
            atomicAdd(a + 1, h2f(pk.y));
            atomicAdd(a + 2, h2f(pk.y >> 16));
            atomicAdd(a + 3, h2f(pk.z));
            atomicAdd(a + 4, h2f(pk.z >> 16));
            atomicAdd(a + 5, h2f(pk.w));
        }
    }
    __syncthreads();

    // phase 2: 4 threads per node, (GSZ*4)/GTPB rounds
    for (int half = 0; half < (GSZ * 4) / GTPB; ++half) {
        int j = half * (GTPB / 4) + (tid >> 2);
        int r = tid & 3;
        int deg = curn[j]; if (deg > CAP) deg = CAP;
        float aZ = 0.f, aL = 0.f, a0 = 0.f, a1 = 0.f, a2 = 0.f, a3 = 0.f;
        for (int s = r; s < deg; s += 4) {
            int i = idx[j * CAP + s];
            uint4 pk = nt_u4(&buckets[s0 + i]);
            aZ += h2f(pk.x >> 16);
            aL += h2f(pk.y);
            a0 += h2f(pk.y >> 16);
            a1 += h2f(pk.z);
            a2 += h2f(pk.z >> 16);
            a3 += h2f(pk.w);
        }
        for (int m = 1; m <= 2; m <<= 1) {
            aZ += __shfl_xor(aZ, m); aL += __shfl_xor(aL, m);
            a0 += __shfl_xor(a0, m); a1 += __shfl_xor(a1, m);
            a2 += __shfl_xor(a2, m); a3 += __shfl_xor(a3, m);
        }
        if (r == 0) {
            int n = b * GSZ + j;
            if (n < N) {
                const float* o = &ovf[j * 7];
                float l = nl[n];
                float ps = __expf(TEMP * l);
                float Z  = aZ + o[0] + ps;
                float sl = aL + o[1] + ps * l;
                float4 q = nq[n];
                float qw = a0 + o[2] + ps * q.x;
                float qx = a1 + o[3] + ps * q.y;
                float qy = a2 + o[4] + ps * q.z;
                float qz = a3 + o[5] + ps * q.w;
                float inv = 1.0f / Z;
                qw *= inv; qx *= inv; qy *= inv; qz *= inv;
                float norm = fmaxf(sqrtf(qw*qw + qx*qx + qy*qy + qz*qz), 1e-12f);
                float rn = 1.0f / norm;
                out_q[n] = make_float4(qw * rn, qx * rn, qy * rn, qz * rn);
                out_l[n] = sl * inv;
            }
        }
    }
}

// ---------------- fallback path (R3) ----------------
__global__ void __launch_bounds__(256)
scatter_kernel(const int* __restrict__ dst, int* __restrict__ cnt,
               int* __restrict__ bucket, int cap,
               const float* __restrict__ node_levels, const float4* __restrict__ node_q,
               const float4* __restrict__ edge_rel_q, const float* __restrict__ edge_w,
               const int* __restrict__ src, float* __restrict__ side, int E) {
    int e = blockIdx.x * blockDim.x + threadIdx.x;
    if (e >= E) return;
    int d = dst[e];
    int slot = atomicAdd(&cnt[d], 1);
    if (slot < cap) {
        bucket[(long long)d * cap + slot] = e;
    } else {
        int s = src[e];
        float l = node_levels[s];
        float p = __expf(TEMP * edge_w[e] * l);
        float ow, ox, oy, oz;
        hamilton(edge_rel_q[e], node_q[s], ow, ox, oy, oz);
        float* rec = side + 6 * (long long)d;
        pk_fadd(rec + 0, p,      p * l);
        pk_fadd(rec + 2, p * ow, p * ox);
        pk_fadd(rec + 4, p * oy, p * oz);
    }
}

__global__ void __launch_bounds__(256)
gather_kernel(const float* __restrict__ node_levels, const float4* __restrict__ node_q,
              const float4* __restrict__ edge_rel_q, const float* __restrict__ edge_w,
              const int* __restrict__ src, const int* __restrict__ cnt,
              const int* __restrict__ bucket, int cap, const float* __restrict__ side,
              float4* __restrict__ out_q, float* __restrict__ out_l, int N) {
    int tid  = blockIdx.x * blockDim.x + threadIdx.x;
    int wave = tid >> 6, lane = tid & 63, half = lane >> 5, sub = lane & 31;
    int n = wave * 2 + half;
    float aZ = 0.f, aL = 0.f, a0 = 0.f, a1 = 0.f, a2 = 0.f, a3 = 0.f;
    if (n < N) {
        int deg = cnt[n]; if (deg > cap) deg = cap;
        const int* bkt = bucket + (long long)n * cap;
        for (int s = sub; s < deg; s += 32) {
            int e = bkt[s];
            int sn = src[e];
            float l = node_levels[sn];
            float p = __expf(TEMP * edge_w[e] * l);
            float ow, ox, oy, oz;
            hamilton(edge_rel_q[e], node_q[sn], ow, ox, oy, oz);
            aZ += p; aL += p * l; a0 += p * ow; a1 += p * ox; a2 += p * oy; a3 += p * oz;
        }
    }
    for (int m = 16; m; m >>= 1) {
        aZ += __shfl_xor(aZ, m); aL += __shfl_xor(aL, m);
        a0 += __shfl_xor(a0, m); a1 += __shfl_xor(a1, m);
        a2 += __shfl_xor(a2, m); a3 += __shfl_xor(a3, m);
    }
    if (sub == 0 && n < N) {
        const float* rec = side + 6 * (long long)n;
        float l  = node_levels[n];
        float ps = __expf(TEMP * l);
        float Z  = aZ + rec[0] + ps;
        float sl = aL + rec[1] + ps * l;
        float4 q = node_q[n];
        float qw = a0 + rec[2] + ps * q.x;
        float qx = a1 + rec[3] + ps * q.y;
        float qy = a2 + rec[4] + ps * q.z;
        float qz = a3 + rec[5] + ps * q.w;
        float inv = 1.0f / Z;
        qw *= inv; qx *= inv; qy *= inv; qz *= inv;
        float norm = fmaxf(sqrtf(qw*qw + qx*qx + qy*qy + qz*qz), 1e-12f);
        float rn = 1.0f / norm;
        out_q[n] = make_float4(qw * rn, qx * rn, qy * rn, qz * rn);
        out_l[n] = sl * inv;
    }
}

extern "C" void kernel_launch(void* const* d_in, const int* in_sizes, int n_in,
                              void* d_out, int out_size, void* d_ws, size_t ws_size,
                              hipStream_t stream) {
    const float*  node_levels = (const float*)d_in[0];
    const float4* node_q      = (const float4*)d_in[1];
    const float4* edge_rel_q  = (const float4*)d_in[2];
    const float*  edge_w      = (const float*)d_in[3];
    const int*    src         = (const int*)d_in[4];
    const int*    dst         = (const int*)d_in[5];

    const int N = in_sizes[0];
    const int E = in_sizes[3];

    const int B = (N + GSZ - 1) / GSZ;            // coarse buckets
    const int span = (E + NBLK - 1) / NBLK;

    // ws layout: blkhist[B*NBLK] u32 | totals[B] | offsets[B+1] | pad | buckets[E] uint4
    size_t head_elems   = (size_t)B * NBLK + B + (B + 1);
    size_t buckets_byte = (head_elems * 4 + 15) & ~(size_t)15;
    size_t need         = buckets_byte + (size_t)E * 16;

    // u16 idx in gather needs per-bucket segment < 65536 records
    bool seg_ok = ((size_t)E / (size_t)B) < 32768;

    if (need <= ws_size && B <= BMAX && seg_ok) {
        unsigned* blkhist = (unsigned*)d_ws;
        unsigned* totals  = blkhist + (size_t)B * NBLK;
        unsigned* offsets = totals + B;
        uint4*    buckets = (uint4*)((char*)d_ws + buckets_byte);

        hist_kernel<<<NBLK, TPB, B * 4, stream>>>(dst, blkhist, E, B, span);
        scan_blocks_kernel<<<B, NBLK, 0, stream>>>(blkhist, totals);
        scan_totals_kernel<<<1, 1024, 0, stream>>>(totals, offsets, B);
        scatter_sort_kernel<<<NBLK, TPB, 0, stream>>>(
            node_levels, node_q, edge_rel_q, edge_w, src, dst,
            blkhist, offsets, buckets, E, B, span);
        gather_pay_kernel<<<B, GTPB, 0, stream>>>(
            node_levels, node_q, offsets, buckets,
            (float4*)d_out, (float*)d_out + 4 * (long long)N, N);
    } else {
        // R3 fallback
        const int tpb = 256;
        size_t cnt_elems  = ((size_t)N + 3) & ~(size_t)3;
        size_t side_elems = 6 * (size_t)N;
        size_t head_bytes = (cnt_elems + side_elems) * 4;
        int cap = 0;
        for (int c : {128, 64}) {
            if (head_bytes + (size_t)N * c * 4 <= ws_size) { cap = c; break; }
        }
        int*   cnt    = (int*)d_ws;
        float* side   = (float*)d_ws + cnt_elems;
        int*   bucket = (int*)d_ws + cnt_elems + side_elems;
        hipMemsetAsync(d_ws, 0, head_bytes, stream);
        scatter_kernel<<<(E + tpb - 1) / tpb, tpb, 0, stream>>>(
            dst, cnt, bucket, cap, node_levels, node_q, edge_rel_q, edge_w, src, side, E);
        int waves  = (N + 1) / 2;
        int blocks = (waves * 64 + tpb - 1) / tpb;
        gather_kernel<<<blocks, tpb, 0, stream>>>(
            node_levels, node_q, edge_rel_q, edge_w, src, cnt, bucket, cap, side,
            (float4*)d_out, (float*)d_out + 4 * (long long)N, N);
    }
}

// Round 9
// 236.702 us; speedup vs baseline: 1.6748x; 1.0427x over previous
//
#include <hip/hip_runtime.h>
#include <hip/hip_fp16.h>

#define TEMP 10.0f
#define TPB 512           // scatter block size
#define HTPB 256          // hist block size
#define NBLK 768          // hist/scatter grid (3 blocks/CU)
#define SHIFT 9
#define GSZ 512           // nodes per bucket = 1<<SHIFT
#define BMAX 256          // max buckets supported by scatter LDS arrays
#define TILE 2048         // edges per scatter tile
#define GTPB 1024         // gather block size
#define CAP 44            // per-node slot capacity in gather (overflow handled)

typedef float v2f  __attribute__((ext_vector_type(2)));
typedef float vf4  __attribute__((ext_vector_type(4)));
typedef unsigned uv4 __attribute__((ext_vector_type(4)));

__device__ __forceinline__ int   nt_i (const int* p)   { return __builtin_nontemporal_load(p); }
__device__ __forceinline__ float nt_f (const float* p) { return __builtin_nontemporal_load(p); }
__device__ __forceinline__ float4 nt_f4(const float4* p) {
    vf4 v = __builtin_nontemporal_load((const vf4*)p);
    return make_float4(v.x, v.y, v.z, v.w);
}
__device__ __forceinline__ uint4 nt_u4(const uint4* p) {
    uv4 v = __builtin_nontemporal_load((const uv4*)p);
    uint4 r; r.x = v.x; r.y = v.y; r.z = v.z; r.w = v.w; return r;
}

__device__ __forceinline__ void pk_fadd(float* p, float a, float b) {
#if __has_builtin(__builtin_amdgcn_global_atomic_fadd_v2f32)
    v2f v; v.x = a; v.y = b;
    __builtin_amdgcn_global_atomic_fadd_v2f32(
        (__attribute__((address_space(1))) v2f*)p, v);
#else
    atomicAdd(p, a); atomicAdd(p + 1, b);
#endif
}

__device__ __forceinline__ void hamilton(float4 a, float4 b,
                                         float& ow, float& ox, float& oy, float& oz) {
    ow = a.x*b.x - a.y*b.y - a.z*b.z - a.w*b.w;
    ox = a.x*b.y + a.y*b.x + a.z*b.w - a.w*b.z;
    oy = a.x*b.z - a.y*b.w + a.z*b.x + a.w*b.y;
    oz = a.x*b.w + a.y*b.z - a.z*b.y + a.w*b.x;
}

__device__ __forceinline__ unsigned f2h(float x) {
    return (unsigned)__half_as_ushort(__float2half_rn(x));
}
__device__ __forceinline__ float h2f(unsigned u) {
    return __half2float(__ushort_as_half((unsigned short)(u & 0xFFFFu)));
}

// ---------- pass H: per-block LDS histogram of dst buckets ----------
__global__ void __launch_bounds__(HTPB)
hist_kernel(const int* __restrict__ dst, unsigned* __restrict__ blkhist,
            int E, int B, int span) {
    extern __shared__ unsigned h[];
    for (int i = threadIdx.x; i < B; i += blockDim.x) h[i] = 0;
    __syncthreads();
    int start = blockIdx.x * span;
    int end = start + span; if (end > E) end = E;
    for (int e = start + threadIdx.x; e < end; e += blockDim.x)
        atomicAdd(&h[((unsigned)nt_i(&dst[e])) >> SHIFT], 1u);
    __syncthreads();
    for (int i = threadIdx.x; i < B; i += blockDim.x)
        blkhist[(size_t)i * gridDim.x + blockIdx.x] = h[i];  // bucket-major
}

// ---------- pass P1: exclusive scan across blocks, per bucket ----------
__global__ void __launch_bounds__(1024)
scan_blocks_kernel(unsigned* __restrict__ blkhist, unsigned* __restrict__ totals) {
    __shared__ unsigned s[1024];
    int b = blockIdx.x, t = threadIdx.x, n = blockDim.x;
    unsigned v = blkhist[(size_t)b * n + t];
    s[t] = v; __syncthreads();
    for (int off = 1; off < n; off <<= 1) {
        unsigned add = (t >= off) ? s[t - off] : 0u;
        __syncthreads();
        s[t] += add;
        __syncthreads();
    }
    blkhist[(size_t)b * n + t] = s[t] - v;   // exclusive (local base)
    if (t == n - 1) totals[b] = s[t];
}

// ---------- pass P2: exclusive scan of bucket totals ----------
__global__ void __launch_bounds__(1024)
scan_totals_kernel(const unsigned* __restrict__ totals,
                   unsigned* __restrict__ offsets, int B) {
    __shared__ unsigned s[1024];
    int t = threadIdx.x;
    unsigned v = (t < B) ? totals[t] : 0u;
    s[t] = v; __syncthreads();
    for (int off = 1; off < 1024; off <<= 1) {
        unsigned add = (t >= off) ? s[t - off] : 0u;
        __syncthreads();
        s[t] += add;
        __syncthreads();
    }
    if (t < B) offsets[t] = s[t] - v;
    if (t == B - 1) offsets[B] = s[t];
}

// ---------- pass S: tile-sorted payload placement (no global atomics) ----------
__global__ void __launch_bounds__(TPB)
scatter_sort_kernel(const float* __restrict__ nl, const float4* __restrict__ nq,
                    const float4* __restrict__ erq, const float* __restrict__ ew,
                    const int* __restrict__ src, const int* __restrict__ dst,
                    const unsigned* __restrict__ blkhist,
                    const unsigned* __restrict__ offsets,
                    uint4* __restrict__ buckets,
                    int E, int B, int span) {
    __shared__ uint4    stage[TILE];     // 32 KB
    __shared__ unsigned gslot[TILE];     //  8 KB
    __shared__ unsigned gcur[BMAX];      //  1 KB each below
    __shared__ unsigned th[BMAX];
    __shared__ unsigned basec[BMAX];
    __shared__ unsigned curt[BMAX];

    int blk = blockIdx.x, nb = gridDim.x, tid = threadIdx.x;
    for (int b = tid; b < B; b += TPB)
        gcur[b] = offsets[b] + blkhist[(size_t)b * nb + blk];
    int start = blk * span;
    int end = start + span; if (end > E) end = E;

    for (int ts = start; ts < end; ts += TILE) {
        int tE = end - ts; if (tE > TILE) tE = TILE;
        for (int b = tid; b < B; b += TPB) th[b] = 0;
        __syncthreads();
        // tile histogram
        for (int k = tid; k < tE; k += TPB)
            atomicAdd(&th[((unsigned)dst[ts + k]) >> SHIFT], 1u);
        __syncthreads();
        // single-wave exclusive scan over B buckets (B <= BMAX = 64*4)
        if (tid < 64) {
            int lane = tid;
            unsigned vals[4];
            unsigned tot = 0;
            #pragma unroll
            for (int c = 0; c < 4; ++c) {
                int i = lane * 4 + c;
                vals[c] = (i < B) ? th[i] : 0u;
                tot += vals[c];
            }
            // inclusive wave scan of tot
            unsigned inc = tot;
            #pragma unroll
            for (int off = 1; off < 64; off <<= 1) {
                unsigned up = __shfl_up(inc, off);
                if (lane >= off) inc += up;
            }
            unsigned run = inc - tot;     // exclusive
            #pragma unroll
            for (int c = 0; c < 4; ++c) {
                int i = lane * 4 + c;
                if (i < B) { basec[i] = run; curt[i] = run; }
                run += vals[c];
            }
        }
        __syncthreads();
        // compute payloads, place bucket-sorted into LDS stage
        for (int k = tid; k < tE; k += TPB) {
            int e = ts + k;
            int s_ = nt_i(&src[e]);
            unsigned d = (unsigned)dst[e];
            float l = nl[s_];
            float p = __expf(TEMP * nt_f(&ew[e]) * l);
            float ow, ox, oy, oz;
            hamilton(nt_f4(&erq[e]), nq[s_], ow, ox, oy, oz);
            unsigned b = d >> SHIFT;
            unsigned pos = atomicAdd(&curt[b], 1u);
            uint4 pk;
            pk.x = (d & (GSZ - 1)) | (f2h(p) << 16);
            pk.y = f2h(p * l)  | (f2h(p * ow) << 16);
            pk.z = f2h(p * ox) | (f2h(p * oy) << 16);
            pk.w = f2h(p * oz);
            stage[pos] = pk;
            gslot[pos] = gcur[b] + (pos - basec[b]);
        }
        __syncthreads();
        // flush in sorted order: consecutive lanes -> consecutive slots
        for (int k = tid; k < tE; k += TPB)
            buckets[gslot[k]] = stage[k];
        __syncthreads();
        for (int b = tid; b < B; b += TPB) gcur[b] += th[b];
        __syncthreads();
    }
}

// ---------- pass G: per-bucket counting-sort by node + register reduce ----------
__global__ void __launch_bounds__(GTPB)
gather_pay_kernel(const float* __restrict__ nl, const float4* __restrict__ nq,
                  const unsigned* __restrict__ offsets,
                  const uint4* __restrict__ buckets,
                  float4* __restrict__ out_q, float* __restrict__ out_l, int N) {
    __shared__ unsigned short idx[GSZ * CAP];   // 45 KB
    __shared__ int   curn[GSZ];                 //  2 KB
    __shared__ float ovf[GSZ * 7];              // 14 KB
    int b = blockIdx.x, tid = threadIdx.x;
    for (int i = tid; i < GSZ; i += GTPB) curn[i] = 0;
    for (int i = tid; i < GSZ * 7; i += GTPB) ovf[i] = 0.f;
    __syncthreads();

    unsigned s0 = offsets[b], s1 = offsets[b + 1];
    int M = (int)(s1 - s0);
    const unsigned* bx = (const unsigned*)(buckets + s0);

    // phase 1: one LDS atomic per record -> per-node index lists
    for (int i = tid; i < M; i += GTPB) {
        unsigned w0 = bx[4 * (size_t)i];
        unsigned dl = w0 & (GSZ - 1);
        int slot = atomicAdd(&curn[dl], 1);
        if (slot < CAP) {
            idx[dl * CAP + slot] = (unsigned short)i;
        } else {
            uint4 pk = buckets[s0 + i];
            float* a = &ovf[dl * 7];
            atomicAdd(a + 0, h2f(pk.x >> 16));
            atomicAdd(a + 1, h2f(pk.y));
            atomicAdd(a + 2, h2f(pk.y >> 16));
            atomicAdd(a + 3, h2f(pk.z));
            atomicAdd(a + 4, h2f(pk.z >> 16));
            atomicAdd(a + 5, h2f(pk.w));
        }
    }
    __syncthreads();

    // phase 2: 4 threads per node, (GSZ*4)/GTPB rounds
    for (int half = 0; half < (GSZ * 4) / GTPB; ++half) {
        int j = half * (GTPB / 4) + (tid >> 2);
        int r = tid & 3;
        int deg = curn[j]; if (deg > CAP) deg = CAP;
        float aZ = 0.f, aL = 0.f, a0 = 0.f, a1 = 0.f, a2 = 0.f, a3 = 0.f;
        for (int s = r; s < deg; s += 4) {
            int i = idx[j * CAP + s];
            uint4 pk = nt_u4(&buckets[s0 + i]);
            aZ += h2f(pk.x >> 16);
            aL += h2f(pk.y);
            a0 += h2f(pk.y >> 16);
            a1 += h2f(pk.z);
            a2 += h2f(pk.z >> 16);
            a3 += h2f(pk.w);
        }
        for (int m = 1; m <= 2; m <<= 1) {
            aZ += __shfl_xor(aZ, m); aL += __shfl_xor(aL, m);
            a0 += __shfl_xor(a0, m); a1 += __shfl_xor(a1, m);
            a2 += __shfl_xor(a2, m); a3 += __shfl_xor(a3, m);
        }
        if (r == 0) {
            int n = b * GSZ + j;
            if (n < N) {
                const float* o = &ovf[j * 7];
                float l = nl[n];
                float ps = __expf(TEMP * l);
                float Z  = aZ + o[0] + ps;
                float sl = aL + o[1] + ps * l;
                float4 q = nq[n];
                float qw = a0 + o[2] + ps * q.x;
                float qx = a1 + o[3] + ps * q.y;
                float qy = a2 + o[4] + ps * q.z;
                float qz = a3 + o[5] + ps * q.w;
                float inv = 1.0f / Z;
                qw *= inv; qx *= inv; qy *= inv; qz *= inv;
                float norm = fmaxf(sqrtf(qw*qw + qx*qx + qy*qy + qz*qz), 1e-12f);
                float rn = 1.0f / norm;
                out_q[n] = make_float4(qw * rn, qx * rn, qy * rn, qz * rn);
                out_l[n] = sl * inv;
            }
        }
    }
}

// ---------------- fallback path (R3) ----------------
__global__ void __launch_bounds__(256)
scatter_kernel(const int* __restrict__ dst, int* __restrict__ cnt,
               int* __restrict__ bucket, int cap,
               const float* __restrict__ node_levels, const float4* __restrict__ node_q,
               const float4* __restrict__ edge_rel_q, const float* __restrict__ edge_w,
               const int* __restrict__ src, float* __restrict__ side, int E) {
    int e = blockIdx.x * blockDim.x + threadIdx.x;
    if (e >= E) return;
    int d = dst[e];
    int slot = atomicAdd(&cnt[d], 1);
    if (slot < cap) {
        bucket[(long long)d * cap + slot] = e;
    } else {
        int s = src[e];
        float l = node_levels[s];
        float p = __expf(TEMP * edge_w[e] * l);
        float ow, ox, oy, oz;
        hamilton(edge_rel_q[e], node_q[s], ow, ox, oy, oz);
        float* rec = side + 6 * (long long)d;
        pk_fadd(rec + 0, p,      p * l);
        pk_fadd(rec + 2, p * ow, p * ox);
        pk_fadd(rec + 4, p * oy, p * oz);
    }
}

__global__ void __launch_bounds__(256)
gather_kernel(const float* __restrict__ node_levels, const float4* __restrict__ node_q,
              const float4* __restrict__ edge_rel_q, const float* __restrict__ edge_w,
              const int* __restrict__ src, const int* __restrict__ cnt,
              const int* __restrict__ bucket, int cap, const float* __restrict__ side,
              float4* __restrict__ out_q, float* __restrict__ out_l, int N) {
    int tid  = blockIdx.x * blockDim.x + threadIdx.x;
    int wave = tid >> 6, lane = tid & 63, half = lane >> 5, sub = lane & 31;
    int n = wave * 2 + half;
    float aZ = 0.f, aL = 0.f, a0 = 0.f, a1 = 0.f, a2 = 0.f, a3 = 0.f;
    if (n < N) {
        int deg = cnt[n]; if (deg > cap) deg = cap;
        const int* bkt = bucket + (long long)n * cap;
        for (int s = sub; s < deg; s += 32) {
            int e = bkt[s];
            int sn = src[e];
            float l = node_levels[sn];
            float p = __expf(TEMP * edge_w[e] * l);
            float ow, ox, oy, oz;
            hamilton(edge_rel_q[e], node_q[sn], ow, ox, oy, oz);
            aZ += p; aL += p * l; a0 += p * ow; a1 += p * ox; a2 += p * oy; a3 += p * oz;
        }
    }
    for (int m = 16; m; m >>= 1) {
        aZ += __shfl_xor(aZ, m); aL += __shfl_xor(aL, m);
        a0 += __shfl_xor(a0, m); a1 += __shfl_xor(a1, m);
        a2 += __shfl_xor(a2, m); a3 += __shfl_xor(a3, m);
    }
    if (sub == 0 && n < N) {
        const float* rec = side + 6 * (long long)n;
        float l  = node_levels[n];
        float ps = __expf(TEMP * l);
        float Z  = aZ + rec[0] + ps;
        float sl = aL + rec[1] + ps * l;
        float4 q = node_q[n];
        float qw = a0 + rec[2] + ps * q.x;
        float qx = a1 + rec[3] + ps * q.y;
        float qy = a2 + rec[4] + ps * q.z;
        float qz = a3 + rec[5] + ps * q.w;
        float inv = 1.0f / Z;
        qw *= inv; qx *= inv; qy *= inv; qz *= inv;
        float norm = fmaxf(sqrtf(qw*qw + qx*qx + qy*qy + qz*qz), 1e-12f);
        float rn = 1.0f / norm;
        out_q[n] = make_float4(qw * rn, qx * rn, qy * rn, qz * rn);
        out_l[n] = sl * inv;
    }
}

extern "C" void kernel_launch(void* const* d_in, const int* in_sizes, int n_in,
                              void* d_out, int out_size, void* d_ws, size_t ws_size,
                              hipStream_t stream) {
    const float*  node_levels = (const float*)d_in[0];
    const float4* node_q      = (const float4*)d_in[1];
    const float4* edge_rel_q  = (const float4*)d_in[2];
    const float*  edge_w      = (const float*)d_in[3];
    const int*    src         = (const int*)d_in[4];
    const int*    dst         = (const int*)d_in[5];

    const int N = in_sizes[0];
    const int E = in_sizes[3];

    const int B = (N + GSZ - 1) / GSZ;            // coarse buckets
    const int span = (E + NBLK - 1) / NBLK;

    // ws layout: blkhist[B*NBLK] u32 | totals[B] | offsets[B+1] | pad | buckets[E] uint4
    size_t head_elems   = (size_t)B * NBLK + B + (B + 1);
    size_t buckets_byte = (head_elems * 4 + 15) & ~(size_t)15;
    size_t need         = buckets_byte + (size_t)E * 16;

    // u16 idx in gather needs per-bucket segment < 65536 records
    bool seg_ok = ((size_t)E / (size_t)B) < 32768;

    if (need <= ws_size && B <= BMAX && seg_ok) {
        unsigned* blkhist = (unsigned*)d_ws;
        unsigned* totals  = blkhist + (size_t)B * NBLK;
        unsigned* offsets = totals + B;
        uint4*    buckets = (uint4*)((char*)d_ws + buckets_byte);

        hist_kernel<<<NBLK, HTPB, B * 4, stream>>>(dst, blkhist, E, B, span);
        scan_blocks_kernel<<<B, NBLK, 0, stream>>>(blkhist, totals);
        scan_totals_kernel<<<1, 1024, 0, stream>>>(totals, offsets, B);
        scatter_sort_kernel<<<NBLK, TPB, 0, stream>>>(
            node_levels, node_q, edge_rel_q, edge_w, src, dst,
            blkhist, offsets, buckets, E, B, span);
        gather_pay_kernel<<<B, GTPB, 0, stream>>>(
            node_levels, node_q, offsets, buckets,
            (float4*)d_out, (float*)d_out + 4 * (long long)N, N);
    } else {
        // R3 fallback
        const int tpb = 256;
        size_t cnt_elems  = ((size_t)N + 3) & ~(size_t)3;
        size_t side_elems = 6 * (size_t)N;
        size_t head_bytes = (cnt_elems + side_elems) * 4;
        int cap = 0;
        for (int c : {128, 64}) {
            if (head_bytes + (size_t)N * c * 4 <= ws_size) { cap = c; break; }
        }
        int*   cnt    = (int*)d_ws;
        float* side   = (float*)d_ws + cnt_elems;
        int*   bucket = (int*)d_ws + cnt_elems + side_elems;
        hipMemsetAsync(d_ws, 0, head_bytes, stream);
        scatter_kernel<<<(E + tpb - 1) / tpb, tpb, 0, stream>>>(
            dst, cnt, bucket, cap, node_levels, node_q, edge_rel_q, edge_w, src, side, E);
        int waves  = (N + 1) / 2;
        int blocks = (waves * 64 + tpb - 1) / tpb;
        gather_kernel<<<blocks, tpb, 0, stream>>>(
            node_levels, node_q, edge_rel_q, edge_w, src, cnt, bucket, cap, side,
            (float4*)d_out, (float*)d_out + 4 * (long long)N, N);
    }
}